// Round 1
// baseline (6060.052 us; speedup 1.0000x reference)
//
#include <hip/hip_runtime.h>
#include <math.h>

// ---- problem constants ----
constexpr int B_ = 64, L_ = 256, T_ = 32, E_ = 384, H_ = 6;
constexpr int DI_ = 768, DS_ = 16, DC_ = 4, DR_ = 24;
constexpr int HID_ = 1536, V_ = 97, ND_ = 12;
constexpr float EPS_ = 1e-5f;
constexpr int HD_ = E_ / H_;        // 64
constexpr int XPN_ = DR_ + 2 * DS_; // 56

__device__ __forceinline__ float siluf(float x) {
    return x / (1.f + expf(-x));
}
__device__ __forceinline__ float softplusf(float x) {
    // logaddexp(x, 0) = max(x,0) + log1p(exp(-|x|))
    return fmaxf(x, 0.f) + log1pf(expf(-fabsf(x)));
}

// ---------------------------------------------------------------------------
// Generic GEMM: C[m,n] = act( sum_k A[m*lda+k] * W[n*K+k] + bias[n] ) + addin
// ACT: 0 none, 1 relu, 2 softplus. bias/addin may be nullptr.
// ---------------------------------------------------------------------------
template <int ACT>
__global__ __launch_bounds__(256) void gemm_tn(
    const float* __restrict__ A, long lda,
    const float* __restrict__ W,
    const float* __restrict__ bias,
    const float* __restrict__ addin,
    float* __restrict__ C,
    int M, int N, int K) {
    constexpr int BM = 64, BN = 64, BK = 16;
    __shared__ float As[BK][BM + 1];
    __shared__ float Bs[BK][BN + 1];

    const int tid = threadIdx.x;
    const int tx = tid & 15, ty = tid >> 4;
    const int bm = blockIdx.x * BM, bn = blockIdx.y * BN;

    float acc[4][4] = {};

    for (int k0 = 0; k0 < K; k0 += BK) {
        // stage A tile (BM x BK)
        for (int i = tid; i < BM * BK; i += 256) {
            int m = i >> 4, k = i & 15;
            int gm = bm + m, gk = k0 + k;
            As[k][m] = (gm < M && gk < K) ? A[(long)gm * lda + gk] : 0.f;
        }
        // stage W tile (BN x BK)
        for (int i = tid; i < BN * BK; i += 256) {
            int n = i >> 4, k = i & 15;
            int gn = bn + n, gk = k0 + k;
            Bs[k][n] = (gn < N && gk < K) ? W[(long)gn * K + gk] : 0.f;
        }
        __syncthreads();
#pragma unroll
        for (int kk = 0; kk < BK; ++kk) {
            float a[4], b[4];
#pragma unroll
            for (int i = 0; i < 4; ++i) a[i] = As[kk][ty * 4 + i];
#pragma unroll
            for (int j = 0; j < 4; ++j) b[j] = Bs[kk][tx * 4 + j];
#pragma unroll
            for (int i = 0; i < 4; ++i)
#pragma unroll
                for (int j = 0; j < 4; ++j) acc[i][j] += a[i] * b[j];
        }
        __syncthreads();
    }

#pragma unroll
    for (int i = 0; i < 4; ++i) {
        int gm = bm + ty * 4 + i;
        if (gm >= M) continue;
#pragma unroll
        for (int j = 0; j < 4; ++j) {
            int gn = bn + tx * 4 + j;
            if (gn >= N) continue;
            float v = acc[i][j];
            if (bias) v += bias[gn];
            if (ACT == 1) v = fmaxf(v, 0.f);
            if (ACT == 2) v = softplusf(v);
            if (addin) v += addin[(long)gm * N + gn];
            C[(long)gm * N + gn] = v;
        }
    }
}

// ---------------------------------------------------------------------------
// hidden = query_embed + pos_emb (broadcast over B); residual = 0
// ---------------------------------------------------------------------------
__global__ void init_kernel(const float* __restrict__ qe,
                            const float* __restrict__ pos,
                            float* __restrict__ hidden,
                            float* __restrict__ residual) {
    long idx = (long)blockIdx.x * 256 + threadIdx.x;
    if (idx >= (long)B_ * T_ * E_) return;
    int te = (int)(idx % ((long)T_ * E_));
    hidden[idx] = qe[te] + pos[te];
    residual[idx] = 0.f;
}

// ---------------------------------------------------------------------------
// residual += hidden_in; hidden_out = rmsnorm(residual) * w   (one block/row)
// ---------------------------------------------------------------------------
__global__ __launch_bounds__(256) void add_rmsnorm_kernel(
    const float* __restrict__ hin, float* __restrict__ residual,
    float* __restrict__ hout, const float* __restrict__ w) {
    const int row = blockIdx.x, tid = threadIdx.x;
    const long base = (long)row * E_;
    __shared__ float red[256];

    float x0 = hin[base + tid] + residual[base + tid];
    bool has1 = (tid + 256 < E_);
    float x1 = has1 ? hin[base + tid + 256] + residual[base + tid + 256] : 0.f;
    residual[base + tid] = x0;
    if (has1) residual[base + tid + 256] = x1;

    red[tid] = x0 * x0 + x1 * x1;
    __syncthreads();
    for (int off = 128; off > 0; off >>= 1) {
        if (tid < off) red[tid] += red[tid + off];
        __syncthreads();
    }
    float sc = rsqrtf(red[0] / E_ + EPS_);
    hout[base + tid] = x0 * sc * w[tid];
    if (has1) hout[base + tid + 256] = x1 * sc * w[tid + 256];
}

// ---------------------------------------------------------------------------
// layernorm: out = (x - mu) * rsqrt(var+eps) * w + b   (one block/row)
// ---------------------------------------------------------------------------
__global__ __launch_bounds__(256) void layernorm_kernel(
    const float* __restrict__ x, const float* __restrict__ w,
    const float* __restrict__ b, float* __restrict__ out) {
    const int row = blockIdx.x, tid = threadIdx.x;
    const long base = (long)row * E_;
    __shared__ float red[256];

    float x0 = x[base + tid];
    bool has1 = (tid + 256 < E_);
    float x1 = has1 ? x[base + tid + 256] : 0.f;

    red[tid] = x0 + x1;
    __syncthreads();
    for (int off = 128; off > 0; off >>= 1) {
        if (tid < off) red[tid] += red[tid + off];
        __syncthreads();
    }
    float mu = red[0] / E_;
    __syncthreads();
    float d0 = x0 - mu, d1 = has1 ? x1 - mu : 0.f;
    red[tid] = d0 * d0 + d1 * d1;
    __syncthreads();
    for (int off = 128; off > 0; off >>= 1) {
        if (tid < off) red[tid] += red[tid + off];
        __syncthreads();
    }
    float sc = rsqrtf(red[0] / E_ + EPS_);
    out[base + tid] = d0 * sc * w[tid] + b[tid];
    if (has1) out[base + tid + 256] = d1 * sc * w[tid + 256] + b[tid + 256];
}

// ---------------------------------------------------------------------------
// depthwise causal conv (DC=4) over xm = xz[..., :DI], + bias, then SiLU
// ---------------------------------------------------------------------------
__global__ void conv_silu_kernel(const float* __restrict__ xz,
                                 const float* __restrict__ cw,
                                 const float* __restrict__ cb,
                                 float* __restrict__ xc) {
    long idx = (long)blockIdx.x * 256 + threadIdx.x;
    if (idx >= (long)B_ * T_ * DI_) return;
    int d = (int)(idx % DI_);
    int t = (int)((idx / DI_) % T_);
    int b = (int)(idx / ((long)DI_ * T_));
    long rowbase = (long)b * T_ * (2 * DI_);
    float acc = cb[d];
#pragma unroll
    for (int k = 0; k < DC_; ++k) {
        int tt = t + k - (DC_ - 1);
        if (tt >= 0) acc += cw[d * DC_ + k] * xz[rowbase + (long)tt * (2 * DI_) + d];
    }
    xc[idx] = siluf(acc);
}

// ---------------------------------------------------------------------------
// selective scan: per (b,d) thread keeps h[16]; fused D*xc and silu(z) gate.
// grid = (DI/256, B), block = 256
// ---------------------------------------------------------------------------
__global__ __launch_bounds__(256) void mamba_scan_kernel(
    const float* __restrict__ dt,   // B*T*DI
    const float* __restrict__ dbl,  // B*T*56 (B at +24, C at +40)
    const float* __restrict__ xc,   // B*T*DI
    const float* __restrict__ xz,   // B*T*1536 (z at +DI)
    const float* __restrict__ Alog, // DI*DS (layer slice)
    const float* __restrict__ Dp,   // DI
    float* __restrict__ y)          // B*T*DI
{
    const int d = blockIdx.x * 256 + threadIdx.x;
    const int b = blockIdx.y;
    __shared__ float Bs[T_][DS_];
    __shared__ float Cs[T_][DS_];
    for (int i = threadIdx.x; i < T_ * DS_; i += 256) {
        int t = i >> 4, s = i & 15;
        long rb = ((long)b * T_ + t) * XPN_;
        Bs[t][s] = dbl[rb + DR_ + s];
        Cs[t][s] = dbl[rb + DR_ + DS_ + s];
    }
    __syncthreads();

    float Aa[DS_];
#pragma unroll
    for (int s = 0; s < DS_; ++s) Aa[s] = -expf(Alog[(long)d * DS_ + s]);
    float h[DS_] = {};
    const float Dv = Dp[d];

    for (int t = 0; t < T_; ++t) {
        long idx = ((long)b * T_ + t) * DI_ + d;
        float dtv = dt[idx];
        float xcv = xc[idx];
        float acc = 0.f;
#pragma unroll
        for (int s = 0; s < DS_; ++s) {
            h[s] = expf(dtv * Aa[s]) * h[s] + dtv * Bs[t][s] * xcv;
            acc += h[s] * Cs[t][s];
        }
        float zv = xz[((long)b * T_ + t) * (2 * DI_) + DI_ + d];
        y[idx] = (acc + Dv * xcv) * siluf(zv);
    }
}

// ---------------------------------------------------------------------------
// cross-attention: one block per (b,h,t); 256 threads = 256 keys.
// ---------------------------------------------------------------------------
__global__ __launch_bounds__(256) void attn_kernel(
    const float* __restrict__ qh,  // B*T*E
    const float* __restrict__ kh,  // B*L*E
    const float* __restrict__ vh,  // B*L*E
    float* __restrict__ ctx)       // B*T*E
{
    const int t = blockIdx.x % T_;
    const int h = (blockIdx.x / T_) % H_;
    const int b = blockIdx.x / (T_ * H_);
    const int tid = threadIdx.x;

    __shared__ float qs[HD_];
    __shared__ float sc[L_];
    __shared__ float red[256];
    __shared__ float part[4][HD_];

    if (tid < HD_) qs[tid] = qh[((long)b * T_ + t) * E_ + h * HD_ + tid];
    __syncthreads();

    const float* krow = kh + ((long)b * L_ + tid) * E_ + h * HD_;
    float dot = 0.f;
#pragma unroll 8
    for (int i = 0; i < HD_; ++i) dot += qs[i] * krow[i];
    dot *= 0.125f; // 1/sqrt(64)

    red[tid] = dot;
    __syncthreads();
    for (int off = 128; off > 0; off >>= 1) {
        if (tid < off) red[tid] = fmaxf(red[tid], red[tid + off]);
        __syncthreads();
    }
    float mx = red[0];
    __syncthreads();

    float e = expf(dot - mx);
    sc[tid] = e;
    red[tid] = e;
    __syncthreads();
    for (int off = 128; off > 0; off >>= 1) {
        if (tid < off) red[tid] += red[tid + off];
        __syncthreads();
    }
    float denom = red[0];

    // ctx[i] = sum_s attn[s] * v[s,i]; 4 s-groups x 64 dims
    const int i = tid & 63, g = tid >> 6;
    const float* vbase = vh + (long)b * L_ * E_ + h * HD_ + i;
    float p = 0.f;
    for (int s = g; s < L_; s += 4) p += sc[s] * vbase[(long)s * E_];
    part[g][i] = p;
    __syncthreads();
    if (tid < HD_) {
        float v = (part[0][tid] + part[1][tid] + part[2][tid] + part[3][tid]) / denom;
        ctx[((long)b * T_ + t) * E_ + h * HD_ + tid] = v;
    }
}

// ---------------------------------------------------------------------------
static void gemm(hipStream_t s, int act, const float* A, long lda,
                 const float* W, const float* bias, const float* addin,
                 float* C, int M, int N, int K) {
    dim3 g((M + 63) / 64, (N + 63) / 64), b(256);
    switch (act) {
        case 0: gemm_tn<0><<<g, b, 0, s>>>(A, lda, W, bias, addin, C, M, N, K); break;
        case 1: gemm_tn<1><<<g, b, 0, s>>>(A, lda, W, bias, addin, C, M, N, K); break;
        case 2: gemm_tn<2><<<g, b, 0, s>>>(A, lda, W, bias, addin, C, M, N, K); break;
    }
}

extern "C" void kernel_launch(void* const* d_in, const int* in_sizes, int n_in,
                              void* d_out, int out_size, void* d_ws, size_t ws_size,
                              hipStream_t stream) {
    const float* enc      = (const float*)d_in[0];
    const float* qe       = (const float*)d_in[1];
    const float* pos      = (const float*)d_in[2];
    const float* m_norm_w = (const float*)d_in[3];
    const float* m_in_w   = (const float*)d_in[4];
    const float* m_conv_w = (const float*)d_in[5];
    const float* m_conv_b = (const float*)d_in[6];
    const float* m_xproj_w= (const float*)d_in[7];
    const float* m_dt_w   = (const float*)d_in[8];
    const float* m_dt_b   = (const float*)d_in[9];
    const float* m_Alog   = (const float*)d_in[10];
    const float* m_D      = (const float*)d_in[11];
    const float* m_out_w  = (const float*)d_in[12];
    const float* rms_w    = (const float*)d_in[13];
    const float* wq = (const float*)d_in[14];
    const float* bq = (const float*)d_in[15];
    const float* wk = (const float*)d_in[16];
    const float* bk = (const float*)d_in[17];
    const float* wv = (const float*)d_in[18];
    const float* bv = (const float*)d_in[19];
    const float* wo = (const float*)d_in[20];
    const float* bo = (const float*)d_in[21];
    const float* ln1_w = (const float*)d_in[22];
    const float* ln1_b = (const float*)d_in[23];
    const float* ffn_w1 = (const float*)d_in[24];
    const float* ffn_b1 = (const float*)d_in[25];
    const float* ffn_w2 = (const float*)d_in[26];
    const float* ffn_b2 = (const float*)d_in[27];
    const float* ln2_w = (const float*)d_in[28];
    const float* ln2_b = (const float*)d_in[29];
    const float* out_w = (const float*)d_in[30];
    const float* out_b = (const float*)d_in[31];

    float* ws = (float*)d_ws;
    const long SZ_BTE = (long)B_ * T_ * E_;       // 786432
    float* hidden   = ws;
    float* residual = ws + SZ_BTE;
    float* S        = ws + 2 * SZ_BTE;

    // mamba-phase scratch (aliased with attention-phase scratch)
    float* xz  = S;                               // B*T*2DI = 3145728
    float* xc  = S + (long)B_ * T_ * 2 * DI_;     // B*T*DI  = 1572864
    float* dbl = xc + (long)B_ * T_ * DI_;        // B*T*56  = 114688
    float* dtb = dbl + (long)B_ * T_ * XPN_;      // B*T*DI
    float* yb  = dtb + (long)B_ * T_ * DI_;       // B*T*DI
    // attention-phase scratch
    float* qh  = S;                                // B*T*E
    float* kh  = S + SZ_BTE;                       // B*L*E = 6291456
    float* vh  = kh + (long)B_ * L_ * E_;          // B*L*E
    float* ctx = vh + (long)B_ * L_ * E_;          // B*T*E
    // ffn scratch
    float* ffnb = S;                               // B*T*HID = 3145728

    const int M = B_ * T_;   // 2048
    const int MK = B_ * L_;  // 16384

    init_kernel<<<(int)((SZ_BTE + 255) / 256), 256, 0, stream>>>(qe, pos, hidden, residual);

    for (int l = 0; l < ND_; ++l) {
        add_rmsnorm_kernel<<<M, 256, 0, stream>>>(hidden, residual, hidden,
                                                  m_norm_w + (long)l * E_);
        gemm(stream, 0, hidden, E_, m_in_w + (long)l * 2 * DI_ * E_,
             nullptr, nullptr, xz, M, 2 * DI_, E_);
        conv_silu_kernel<<<(M * DI_ + 255) / 256, 256, 0, stream>>>(
            xz, m_conv_w + (long)l * DI_ * DC_, m_conv_b + (long)l * DI_, xc);
        gemm(stream, 0, xc, DI_, m_xproj_w + (long)l * XPN_ * DI_,
             nullptr, nullptr, dbl, M, XPN_, DI_);
        gemm(stream, 2, dbl, XPN_, m_dt_w + (long)l * DI_ * DR_,
             m_dt_b + (long)l * DI_, nullptr, dtb, M, DI_, DR_);
        mamba_scan_kernel<<<dim3(DI_ / 256, B_), 256, 0, stream>>>(
            dtb, dbl, xc, xz, m_Alog + (long)l * DI_ * DS_, m_D + (long)l * DI_, yb);
        gemm(stream, 0, yb, DI_, m_out_w + (long)l * E_ * DI_,
             nullptr, nullptr, hidden, M, E_, DI_);
    }

    add_rmsnorm_kernel<<<M, 256, 0, stream>>>(hidden, residual, hidden, rms_w);

    gemm(stream, 0, hidden, E_, wq, bq, nullptr, qh, M, E_, E_);
    gemm(stream, 0, enc, E_, wk, bk, nullptr, kh, MK, E_, E_);
    gemm(stream, 0, enc, E_, wv, bv, nullptr, vh, MK, E_, E_);
    attn_kernel<<<B_ * H_ * T_, 256, 0, stream>>>(qh, kh, vh, ctx);
    gemm(stream, 0, ctx, E_, wo, bo, residual, residual, M, E_, E_);

    layernorm_kernel<<<M, 256, 0, stream>>>(residual, ln1_w, ln1_b, hidden);
    gemm(stream, 1, hidden, E_, ffn_w1, ffn_b1, nullptr, ffnb, M, HID_, E_);
    gemm(stream, 0, ffnb, HID_, ffn_w2, ffn_b2, residual, residual, M, E_, HID_);
    layernorm_kernel<<<M, 256, 0, stream>>>(residual, ln2_w, ln2_b, hidden);

    gemm(stream, 0, hidden, E_, out_w, out_b, nullptr, (float*)d_out, M, V_, E_);
}

// Round 2
// 1881.888 us; speedup vs baseline: 3.2202x; 3.2202x over previous
//
#include <hip/hip_runtime.h>
#include <math.h>

// ---- problem constants ----
constexpr int B_ = 64, L_ = 256, T_ = 32, E_ = 384, H_ = 6;
constexpr int DI_ = 768, DS_ = 16, DC_ = 4, DR_ = 24;
constexpr int HID_ = 1536, V_ = 97, ND_ = 12;
constexpr float EPS_ = 1e-5f;
constexpr int HD_ = E_ / H_;        // 64
constexpr int XPN_ = DR_ + 2 * DS_; // 56

typedef __attribute__((ext_vector_type(8))) short  short8;   // 8 bf16 = 4 VGPRs
typedef __attribute__((ext_vector_type(4))) float  floatx4;
typedef __attribute__((ext_vector_type(8))) unsigned short ushort8v;

__device__ __forceinline__ float siluf(float x) { return x / (1.f + expf(-x)); }
__device__ __forceinline__ float softplusf(float x) {
    return fmaxf(x, 0.f) + log1pf(expf(-fabsf(x)));
}
// fp32 -> bf16 bits, round-to-nearest-even
__device__ __forceinline__ unsigned short f2bf(float f) {
    unsigned int u = __float_as_uint(f);
    u += 0x7fffu + ((u >> 16) & 1u);
    return (unsigned short)(u >> 16);
}
// bf16 bits -> fp32 (exact)
__device__ __forceinline__ float bf2f(unsigned short u) {
    return __uint_as_float(((unsigned int)u) << 16);
}

// ---------------------------------------------------------------------------
// fp32 -> bf16 weight conversion (n must be divisible by 4)
// ---------------------------------------------------------------------------
__global__ __launch_bounds__(256) void cvt_bf16_kernel(
    const float* __restrict__ src, unsigned short* __restrict__ dst, long n4) {
    long i = (long)blockIdx.x * 256 + threadIdx.x;
    if (i >= n4) return;
    float4 v = ((const float4*)src)[i];
    __attribute__((ext_vector_type(4))) unsigned short o;
    o[0] = f2bf(v.x); o[1] = f2bf(v.y); o[2] = f2bf(v.z); o[3] = f2bf(v.w);
    *(__attribute__((ext_vector_type(4))) unsigned short*)(dst + i * 4) = o;
}

// ---------------------------------------------------------------------------
// bf16 MFMA GEMM: C[m,n] = act( sum_k A_f32[m,k] * W_bf16[n,k] + bias[n] ) + addin
// A fp32 (converted to bf16 in staging), W pre-converted bf16 [N][K].
// ACT: 0 none, 1 relu, 2 softplus. OBF: 1 -> bf16 output, else fp32.
// Requires M % 64 == 0. N, K arbitrary (zero-padded in LDS).
// ---------------------------------------------------------------------------
template <int ACT, int OBF>
__global__ __launch_bounds__(256) void gemm_mfma(
    const float* __restrict__ A, int lda,
    const unsigned short* __restrict__ W,
    const float* __restrict__ bias,
    const float* __restrict__ addin,
    void* __restrict__ Cv,
    int M, int N, int K) {
    constexpr int BM = 64, BN = 64, BK = 64;
    constexpr int LDK = BK + 8;  // 72 bf16 = 144 B row stride (breaks pow2 banks)
    __shared__ unsigned short As[BM][LDK];
    __shared__ unsigned short Bs[BN][LDK];

    const int tid = threadIdx.x;
    const int wave = tid >> 6, lane = tid & 63;
    const int bm = blockIdx.x * BM, bn = blockIdx.y * BN;
    const int wm = (wave & 1) * 32, wn = (wave >> 1) * 32;
    const int lm = lane & 15, quad = lane >> 4;

    // staging map: 4 threads per row, 16 elements each
    const int srow = tid >> 2, skc = (tid & 3) * 16;

    floatx4 acc[2][2] = {};

    for (int k0 = 0; k0 < K; k0 += BK) {
        // ---- stage A tile (fp32 -> bf16) ----
        {
            const int gm = bm + srow;
            const float* ap = A + (long)gm * lda + k0 + skc;
            if (k0 + skc + 16 <= K) {
                ushort8v o0, o1;
#pragma unroll
                for (int i = 0; i < 2; ++i) {
                    float4 v = ((const float4*)ap)[i];
                    o0[i * 4 + 0] = f2bf(v.x); o0[i * 4 + 1] = f2bf(v.y);
                    o0[i * 4 + 2] = f2bf(v.z); o0[i * 4 + 3] = f2bf(v.w);
                }
#pragma unroll
                for (int i = 0; i < 2; ++i) {
                    float4 v = ((const float4*)ap)[2 + i];
                    o1[i * 4 + 0] = f2bf(v.x); o1[i * 4 + 1] = f2bf(v.y);
                    o1[i * 4 + 2] = f2bf(v.z); o1[i * 4 + 3] = f2bf(v.w);
                }
                *(ushort8v*)&As[srow][skc] = o0;
                *(ushort8v*)&As[srow][skc + 8] = o1;
            } else {
#pragma unroll
                for (int i = 0; i < 16; ++i)
                    As[srow][skc + i] = (k0 + skc + i < K) ? f2bf(ap[i]) : (unsigned short)0;
            }
        }
        // ---- stage W tile (bf16 copy) ----
        {
            const int gn = bn + srow;
            const unsigned short* wp = W + (long)gn * K + k0 + skc;
            if (gn < N && k0 + skc + 16 <= K) {
                uint4 u0 = ((const uint4*)wp)[0];
                uint4 u1 = ((const uint4*)wp)[1];
                *(uint4*)&Bs[srow][skc] = u0;
                *(uint4*)&Bs[srow][skc + 8] = u1;
            } else {
#pragma unroll
                for (int i = 0; i < 16; ++i)
                    Bs[srow][skc + i] =
                        (gn < N && k0 + skc + i < K) ? wp[i] : (unsigned short)0;
            }
        }
        __syncthreads();
#pragma unroll
        for (int ks = 0; ks < BK; ks += 32) {
            short8 a0 = *(const short8*)&As[wm + lm][ks + quad * 8];
            short8 a1 = *(const short8*)&As[wm + 16 + lm][ks + quad * 8];
            short8 b0 = *(const short8*)&Bs[wn + lm][ks + quad * 8];
            short8 b1 = *(const short8*)&Bs[wn + 16 + lm][ks + quad * 8];
            acc[0][0] = __builtin_amdgcn_mfma_f32_16x16x32_bf16(a0, b0, acc[0][0], 0, 0, 0);
            acc[0][1] = __builtin_amdgcn_mfma_f32_16x16x32_bf16(a0, b1, acc[0][1], 0, 0, 0);
            acc[1][0] = __builtin_amdgcn_mfma_f32_16x16x32_bf16(a1, b0, acc[1][0], 0, 0, 0);
            acc[1][1] = __builtin_amdgcn_mfma_f32_16x16x32_bf16(a1, b1, acc[1][1], 0, 0, 0);
        }
        __syncthreads();
    }

    // epilogue: C/D layout col=lane&15, row=quad*4+reg  [m89-verified]
#pragma unroll
    for (int sm = 0; sm < 2; ++sm) {
#pragma unroll
        for (int sn = 0; sn < 2; ++sn) {
            const int gn = bn + wn + sn * 16 + lm;
            if (gn >= N) continue;
#pragma unroll
            for (int r = 0; r < 4; ++r) {
                const int gm = bm + wm + sm * 16 + quad * 4 + r;
                float v = acc[sm][sn][r];
                if (bias) v += bias[gn];
                if (ACT == 1) v = fmaxf(v, 0.f);
                if (ACT == 2) v = softplusf(v);
                if (addin) v += addin[(long)gm * N + gn];
                if (OBF)
                    ((unsigned short*)Cv)[(long)gm * N + gn] = f2bf(v);
                else
                    ((float*)Cv)[(long)gm * N + gn] = v;
            }
        }
    }
}

// ---------------------------------------------------------------------------
// hidden = query_embed + pos_emb (broadcast over B); residual = 0
// ---------------------------------------------------------------------------
__global__ void init_kernel(const float* __restrict__ qe,
                            const float* __restrict__ pos,
                            float* __restrict__ hidden,
                            float* __restrict__ residual) {
    long idx = (long)blockIdx.x * 256 + threadIdx.x;
    if (idx >= (long)B_ * T_ * E_) return;
    int te = (int)(idx % ((long)T_ * E_));
    hidden[idx] = qe[te] + pos[te];
    residual[idx] = 0.f;
}

// ---------------------------------------------------------------------------
// residual += hidden_in; hidden_out = rmsnorm(residual) * w   (one block/row)
// ---------------------------------------------------------------------------
__global__ __launch_bounds__(256) void add_rmsnorm_kernel(
    const float* __restrict__ hin, float* __restrict__ residual,
    float* __restrict__ hout, const float* __restrict__ w) {
    const int row = blockIdx.x, tid = threadIdx.x;
    const long base = (long)row * E_;
    __shared__ float red[256];

    float x0 = hin[base + tid] + residual[base + tid];
    bool has1 = (tid + 256 < E_);
    float x1 = has1 ? hin[base + tid + 256] + residual[base + tid + 256] : 0.f;
    residual[base + tid] = x0;
    if (has1) residual[base + tid + 256] = x1;

    red[tid] = x0 * x0 + x1 * x1;
    __syncthreads();
    for (int off = 128; off > 0; off >>= 1) {
        if (tid < off) red[tid] += red[tid + off];
        __syncthreads();
    }
    float sc = rsqrtf(red[0] / E_ + EPS_);
    hout[base + tid] = x0 * sc * w[tid];
    if (has1) hout[base + tid + 256] = x1 * sc * w[tid + 256];
}

// ---------------------------------------------------------------------------
// layernorm (one block/row)
// ---------------------------------------------------------------------------
__global__ __launch_bounds__(256) void layernorm_kernel(
    const float* __restrict__ x, const float* __restrict__ w,
    const float* __restrict__ b, float* __restrict__ out) {
    const int row = blockIdx.x, tid = threadIdx.x;
    const long base = (long)row * E_;
    __shared__ float red[256];

    float x0 = x[base + tid];
    bool has1 = (tid + 256 < E_);
    float x1 = has1 ? x[base + tid + 256] : 0.f;

    red[tid] = x0 + x1;
    __syncthreads();
    for (int off = 128; off > 0; off >>= 1) {
        if (tid < off) red[tid] += red[tid + off];
        __syncthreads();
    }
    float mu = red[0] / E_;
    __syncthreads();
    float d0 = x0 - mu, d1 = has1 ? x1 - mu : 0.f;
    red[tid] = d0 * d0 + d1 * d1;
    __syncthreads();
    for (int off = 128; off > 0; off >>= 1) {
        if (tid < off) red[tid] += red[tid + off];
        __syncthreads();
    }
    float sc = rsqrtf(red[0] / E_ + EPS_);
    out[base + tid] = d0 * sc * w[tid] + b[tid];
    if (has1) out[base + tid + 256] = d1 * sc * w[tid + 256] + b[tid + 256];
}

// ---------------------------------------------------------------------------
// depthwise causal conv (DC=4) over xm = xz[..., :DI], + bias, then SiLU
// ---------------------------------------------------------------------------
__global__ void conv_silu_kernel(const float* __restrict__ xz,
                                 const float* __restrict__ cw,
                                 const float* __restrict__ cb,
                                 float* __restrict__ xc) {
    long idx = (long)blockIdx.x * 256 + threadIdx.x;
    if (idx >= (long)B_ * T_ * DI_) return;
    int d = (int)(idx % DI_);
    int t = (int)((idx / DI_) % T_);
    int b = (int)(idx / ((long)DI_ * T_));
    long rowbase = (long)b * T_ * (2 * DI_);
    float acc = cb[d];
#pragma unroll
    for (int k = 0; k < DC_; ++k) {
        int tt = t + k - (DC_ - 1);
        if (tt >= 0) acc += cw[d * DC_ + k] * xz[rowbase + (long)tt * (2 * DI_) + d];
    }
    xc[idx] = siluf(acc);
}

// ---------------------------------------------------------------------------
// selective scan: per (b,d) thread keeps h[16]; fused D*xc and silu(z) gate.
// grid = (DI/256, B), block = 256
// ---------------------------------------------------------------------------
__global__ __launch_bounds__(256) void mamba_scan_kernel(
    const float* __restrict__ dt,   // B*T*DI
    const float* __restrict__ dbl,  // B*T*56 (B at +24, C at +40)
    const float* __restrict__ xc,   // B*T*DI
    const float* __restrict__ xz,   // B*T*1536 (z at +DI)
    const float* __restrict__ Alog, // DI*DS (layer slice)
    const float* __restrict__ Dp,   // DI
    float* __restrict__ y)          // B*T*DI
{
    const int d = blockIdx.x * 256 + threadIdx.x;
    const int b = blockIdx.y;
    __shared__ float Bs[T_][DS_];
    __shared__ float Cs[T_][DS_];
    for (int i = threadIdx.x; i < T_ * DS_; i += 256) {
        int t = i >> 4, s = i & 15;
        long rb = ((long)b * T_ + t) * XPN_;
        Bs[t][s] = dbl[rb + DR_ + s];
        Cs[t][s] = dbl[rb + DR_ + DS_ + s];
    }
    __syncthreads();

    float Aa[DS_];
#pragma unroll
    for (int s = 0; s < DS_; ++s) Aa[s] = -expf(Alog[(long)d * DS_ + s]);
    float h[DS_] = {};
    const float Dv = Dp[d];

    for (int t = 0; t < T_; ++t) {
        long idx = ((long)b * T_ + t) * DI_ + d;
        float dtv = dt[idx];
        float xcv = xc[idx];
        float acc = 0.f;
#pragma unroll
        for (int s = 0; s < DS_; ++s) {
            h[s] = expf(dtv * Aa[s]) * h[s] + dtv * Bs[t][s] * xcv;
            acc += h[s] * Cs[t][s];
        }
        float zv = xz[((long)b * T_ + t) * (2 * DI_) + DI_ + d];
        y[idx] = (acc + Dv * xcv) * siluf(zv);
    }
}

// ---------------------------------------------------------------------------
// cross-attention: one block per (b,h,t); 256 threads = 256 keys. K/V in bf16.
// ---------------------------------------------------------------------------
__global__ __launch_bounds__(256) void attn_kernel(
    const float* __restrict__ qh,            // B*T*E fp32
    const unsigned short* __restrict__ kh,   // B*L*E bf16
    const unsigned short* __restrict__ vh,   // B*L*E bf16
    float* __restrict__ ctx)                 // B*T*E fp32
{
    const int t = blockIdx.x % T_;
    const int h = (blockIdx.x / T_) % H_;
    const int b = blockIdx.x / (T_ * H_);
    const int tid = threadIdx.x;

    __shared__ float qs[HD_];
    __shared__ float sc[L_];
    __shared__ float red[256];
    __shared__ float part[4][HD_];

    if (tid < HD_) qs[tid] = qh[((long)b * T_ + t) * E_ + h * HD_ + tid];
    __syncthreads();

    const unsigned short* krow = kh + ((long)b * L_ + tid) * E_ + h * HD_;
    float dot = 0.f;
#pragma unroll
    for (int c = 0; c < 8; ++c) {  // 8 x uint4 = 64 bf16
        uint4 u = ((const uint4*)krow)[c];
        const unsigned int uu[4] = {u.x, u.y, u.z, u.w};
#pragma unroll
        for (int j = 0; j < 4; ++j) {
            float lo = __uint_as_float(uu[j] << 16);
            float hi = __uint_as_float(uu[j] & 0xffff0000u);
            dot += qs[c * 8 + j * 2] * lo + qs[c * 8 + j * 2 + 1] * hi;
        }
    }
    dot *= 0.125f;  // 1/sqrt(64)

    red[tid] = dot;
    __syncthreads();
    for (int off = 128; off > 0; off >>= 1) {
        if (tid < off) red[tid] = fmaxf(red[tid], red[tid + off]);
        __syncthreads();
    }
    float mx = red[0];
    __syncthreads();

    float e = expf(dot - mx);
    sc[tid] = e;
    red[tid] = e;
    __syncthreads();
    for (int off = 128; off > 0; off >>= 1) {
        if (tid < off) red[tid] += red[tid + off];
        __syncthreads();
    }
    float denom = red[0];

    const int i = tid & 63, g = tid >> 6;
    const unsigned short* vbase = vh + (long)b * L_ * E_ + h * HD_ + i;
    float p = 0.f;
    for (int s = g; s < L_; s += 4) p += sc[s] * bf2f(vbase[(long)s * E_]);
    part[g][i] = p;
    __syncthreads();
    if (tid < HD_) {
        float v = (part[0][tid] + part[1][tid] + part[2][tid] + part[3][tid]) / denom;
        ctx[((long)b * T_ + t) * E_ + h * HD_ + tid] = v;
    }
}

// ---------------------------------------------------------------------------
static void gemm(hipStream_t s, int act, int obf, const float* A, int lda,
                 const unsigned short* W, const float* bias, const float* addin,
                 void* C, int M, int N, int K) {
    dim3 g(M / 64, (N + 63) / 64), b(256);
    if (obf) {
        gemm_mfma<0, 1><<<g, b, 0, s>>>(A, lda, W, bias, addin, C, M, N, K);
        return;
    }
    switch (act) {
        case 0: gemm_mfma<0, 0><<<g, b, 0, s>>>(A, lda, W, bias, addin, C, M, N, K); break;
        case 1: gemm_mfma<1, 0><<<g, b, 0, s>>>(A, lda, W, bias, addin, C, M, N, K); break;
        case 2: gemm_mfma<2, 0><<<g, b, 0, s>>>(A, lda, W, bias, addin, C, M, N, K); break;
    }
}

static void cvt(hipStream_t s, const float* src, unsigned short* dst, long n) {
    long n4 = n / 4;
    cvt_bf16_kernel<<<(int)((n4 + 255) / 256), 256, 0, s>>>(src, dst, n4);
}

extern "C" void kernel_launch(void* const* d_in, const int* in_sizes, int n_in,
                              void* d_out, int out_size, void* d_ws, size_t ws_size,
                              hipStream_t stream) {
    const float* enc      = (const float*)d_in[0];
    const float* qe       = (const float*)d_in[1];
    const float* pos      = (const float*)d_in[2];
    const float* m_norm_w = (const float*)d_in[3];
    const float* m_in_w   = (const float*)d_in[4];
    const float* m_conv_w = (const float*)d_in[5];
    const float* m_conv_b = (const float*)d_in[6];
    const float* m_xproj_w= (const float*)d_in[7];
    const float* m_dt_w   = (const float*)d_in[8];
    const float* m_dt_b   = (const float*)d_in[9];
    const float* m_Alog   = (const float*)d_in[10];
    const float* m_D      = (const float*)d_in[11];
    const float* m_out_w  = (const float*)d_in[12];
    const float* rms_w    = (const float*)d_in[13];
    const float* wq = (const float*)d_in[14];
    const float* bq = (const float*)d_in[15];
    const float* wk = (const float*)d_in[16];
    const float* bk = (const float*)d_in[17];
    const float* wv = (const float*)d_in[18];
    const float* bv = (const float*)d_in[19];
    const float* wo = (const float*)d_in[20];
    const float* bo = (const float*)d_in[21];
    const float* ln1_w = (const float*)d_in[22];
    const float* ln1_b = (const float*)d_in[23];
    const float* ffn_w1 = (const float*)d_in[24];
    const float* ffn_b1 = (const float*)d_in[25];
    const float* ffn_w2 = (const float*)d_in[26];
    const float* ffn_b2 = (const float*)d_in[27];
    const float* ln2_w = (const float*)d_in[28];
    const float* ln2_b = (const float*)d_in[29];
    const float* out_w = (const float*)d_in[30];
    const float* out_b = (const float*)d_in[31];

    float* ws = (float*)d_ws;
    const long SZ_BTE = (long)B_ * T_ * E_;  // 786432
    float* hidden   = ws;
    float* residual = ws + SZ_BTE;
    float* S        = ws + 2 * SZ_BTE;       // 7,979,008 floats of phase scratch

    // mamba-phase scratch
    float* xz  = S;                               // B*T*2DI = 3145728
    float* xc  = S + (long)B_ * T_ * 2 * DI_;     // B*T*DI  = 1572864
    float* dbl = xc + (long)B_ * T_ * DI_;        // B*T*56  = 114688
    float* dtb = dbl + (long)B_ * T_ * XPN_;      // B*T*DI
    float* yb  = dtb + (long)B_ * T_ * DI_;       // B*T*DI
    const long S_FLOATS = 3145728 + 1572864 + 114688 + 1572864 + 1572864; // 7,979,008
    // attention-phase scratch (aliases mamba scratch)
    float* qh  = S;                                // B*T*E fp32
    float* ctx = S + SZ_BTE;                       // B*T*E fp32
    unsigned short* kh = (unsigned short*)(S + 2 * SZ_BTE);   // B*L*E bf16
    unsigned short* vh = kh + (long)B_ * L_ * E_;             // B*L*E bf16
    // ffn scratch
    float* ffnb = S;                               // B*T*HID

    // bf16 weight region, after all fp32 scratch
    unsigned short* wbf = (unsigned short*)(S + S_FLOATS);
    unsigned short* w_in    = wbf;                      // 12*1536*384 = 7,077,888
    unsigned short* w_xproj = w_in    + 7077888;        // 12*56*768   =   516,096
    unsigned short* w_dt    = w_xproj + 516096;         // 12*768*24   =   221,184
    unsigned short* w_out   = w_dt    + 221184;         // 12*384*768  = 3,538,944
    unsigned short* w_q     = w_out   + 3538944;        // 384*384     =   147,456
    unsigned short* w_k     = w_q     + 147456;
    unsigned short* w_v     = w_k     + 147456;
    unsigned short* w_o     = w_v     + 147456;
    unsigned short* w_f1    = w_o     + 147456;         // 1536*384    =   589,824
    unsigned short* w_f2    = w_f1    + 589824;         // 384*1536    =   589,824
    unsigned short* w_lg    = w_f2    + 589824;         // 97*384      =    37,248

    const int M  = B_ * T_;   // 2048
    const int MK = B_ * L_;   // 16384

    // ---- weight conversion (every launch: ws is re-poisoned) ----
    cvt(stream, m_in_w,    w_in,    7077888);
    cvt(stream, m_xproj_w, w_xproj, 516096);
    cvt(stream, m_dt_w,    w_dt,    221184);
    cvt(stream, m_out_w,   w_out,   3538944);
    cvt(stream, wq, w_q, 147456);
    cvt(stream, wk, w_k, 147456);
    cvt(stream, wv, w_v, 147456);
    cvt(stream, wo, w_o, 147456);
    cvt(stream, ffn_w1, w_f1, 589824);
    cvt(stream, ffn_w2, w_f2, 589824);
    cvt(stream, out_w,  w_lg, 37248);

    init_kernel<<<(int)((SZ_BTE + 255) / 256), 256, 0, stream>>>(qe, pos, hidden, residual);

    for (int l = 0; l < ND_; ++l) {
        add_rmsnorm_kernel<<<M, 256, 0, stream>>>(hidden, residual, hidden,
                                                  m_norm_w + (long)l * E_);
        gemm(stream, 0, 0, hidden, E_, w_in + (long)l * 2 * DI_ * E_,
             nullptr, nullptr, xz, M, 2 * DI_, E_);
        conv_silu_kernel<<<(M * DI_ + 255) / 256, 256, 0, stream>>>(
            xz, m_conv_w + (long)l * DI_ * DC_, m_conv_b + (long)l * DI_, xc);
        gemm(stream, 0, 0, xc, DI_, w_xproj + (long)l * XPN_ * DI_,
             nullptr, nullptr, dbl, M, XPN_, DI_);
        gemm(stream, 2, 0, dbl, XPN_, w_dt + (long)l * DI_ * DR_,
             m_dt_b + (long)l * DI_, nullptr, dtb, M, DI_, DR_);
        mamba_scan_kernel<<<dim3(DI_ / 256, B_), 256, 0, stream>>>(
            dtb, dbl, xc, xz, m_Alog + (long)l * DI_ * DS_, m_D + (long)l * DI_, yb);
        gemm(stream, 0, 0, yb, DI_, w_out + (long)l * E_ * DI_,
             nullptr, nullptr, hidden, M, E_, DI_);
    }

    add_rmsnorm_kernel<<<M, 256, 0, stream>>>(hidden, residual, hidden, rms_w);

    gemm(stream, 0, 0, hidden, E_, w_q, bq, nullptr, qh, M, E_, E_);
    gemm(stream, 0, 1, enc, E_, w_k, bk, nullptr, kh, MK, E_, E_);
    gemm(stream, 0, 1, enc, E_, w_v, bv, nullptr, vh, MK, E_, E_);
    attn_kernel<<<B_ * H_ * T_, 256, 0, stream>>>(qh, kh, vh, ctx);
    gemm(stream, 0, 0, ctx, E_, w_o, bo, residual, residual, M, E_, E_);

    layernorm_kernel<<<M, 256, 0, stream>>>(residual, ln1_w, ln1_b, hidden);
    gemm(stream, 1, 0, hidden, E_, w_f1, ffn_b1, nullptr, ffnb, M, HID_, E_);
    gemm(stream, 0, 0, ffnb, HID_, w_f2, ffn_b2, residual, residual, M, E_, HID_);
    layernorm_kernel<<<M, 256, 0, stream>>>(residual, ln2_w, ln2_b, hidden);

    gemm(stream, 0, 0, hidden, E_, w_lg, out_b, nullptr, (float*)d_out, M, V_, E_);
}

// Round 3
// 1421.404 us; speedup vs baseline: 4.2634x; 1.3240x over previous
//
#include <hip/hip_runtime.h>
#include <math.h>

// ---- problem constants ----
constexpr int B_ = 64, L_ = 256, T_ = 32, E_ = 384, H_ = 6;
constexpr int DI_ = 768, DS_ = 16, DC_ = 4, DR_ = 24;
constexpr int HID_ = 1536, V_ = 97, ND_ = 12;
constexpr float EPS_ = 1e-5f;
constexpr int HD_ = 64;

typedef unsigned short ushort_t;
typedef __attribute__((ext_vector_type(8))) short  short8;
typedef __attribute__((ext_vector_type(4))) float  floatx4;
typedef __attribute__((ext_vector_type(8))) unsigned short ushort8v;

__device__ __forceinline__ float siluf(float x) { return x / (1.f + expf(-x)); }
__device__ __forceinline__ float softplusf(float x) {
    return fmaxf(x, 0.f) + log1pf(expf(-fabsf(x)));
}
__device__ __forceinline__ ushort_t f2bf(float f) {
    unsigned int u = __float_as_uint(f);
    u += 0x7fffu + ((u >> 16) & 1u);
    return (ushort_t)(u >> 16);
}
__device__ __forceinline__ float bf2f(ushort_t u) {
    return __uint_as_float(((unsigned int)u) << 16);
}
__device__ __forceinline__ void unpack2(unsigned int w, float& lo, float& hi) {
    lo = __uint_as_float(w << 16);
    hi = __uint_as_float(w & 0xffff0000u);
}
// async global->LDS, 16B per lane; lds dest = wave-uniform base + lane*16
__device__ __forceinline__ void gl_lds16(const ushort_t* g, ushort_t* l) {
    __builtin_amdgcn_global_load_lds(
        (const __attribute__((address_space(1))) unsigned int*)g,
        (__attribute__((address_space(3))) unsigned int*)l, 16, 0, 0);
}

// ---------------------------------------------------------------------------
// fp32 -> bf16 (vectorized, n divisible by 4)
// ---------------------------------------------------------------------------
__global__ __launch_bounds__(256) void cvt_bf16_kernel(
    const float* __restrict__ src, ushort_t* __restrict__ dst, long n4) {
    long i = (long)blockIdx.x * 256 + threadIdx.x;
    if (i >= n4) return;
    float4 v = ((const float4*)src)[i];
    __attribute__((ext_vector_type(4))) unsigned short o;
    o[0] = f2bf(v.x); o[1] = f2bf(v.y); o[2] = f2bf(v.z); o[3] = f2bf(v.w);
    *(__attribute__((ext_vector_type(4))) unsigned short*)(dst + i * 4) = o;
}

// fp32 -> bf16 with per-layer zero padding
__global__ __launch_bounds__(256) void cvt_pad_kernel(
    const float* __restrict__ src, ushort_t* __restrict__ dst,
    int sr, int sc, int dr, int dc, int layers) {
    long total = (long)layers * dr * dc;
    long idx = (long)blockIdx.x * 256 + threadIdx.x;
    if (idx >= total) return;
    int l = (int)(idx / ((long)dr * dc));
    int rem = (int)(idx % ((long)dr * dc));
    int r = rem / dc, c = rem % dc;
    float v = (r < sr && c < sc) ? src[((long)l * sr + r) * sc + c] : 0.f;
    dst[idx] = f2bf(v);
}

// ---------------------------------------------------------------------------
// bf16 MFMA GEMM with global_load_lds staging + XOR swizzle.
// C[m,n] = act( sum_k A[m,k]*W[n,k] + bias[n] ) + addin ; zero-fill N<=gn<Nz.
// A bf16 [M][lda], W bf16 [Nz_rounded][K]. K % 64 == 0, M % 64 == 0.
// ACT: 0 none, 1 relu, 2 softplus. OBF: 1 bf16 out, 0 fp32 out.
// ---------------------------------------------------------------------------
template <int ACT, int OBF>
__global__ __launch_bounds__(256) void gemm_bf16(
    const ushort_t* __restrict__ A, int lda,
    const ushort_t* __restrict__ W,
    const float* __restrict__ bias,
    const float* __restrict__ addin,
    void* __restrict__ Cv,
    int M, int N, int K, int Nz, int ldc) {
    __shared__ ushort_t As[64 * 64];
    __shared__ ushort_t Bs[64 * 64];

    const int tid = threadIdx.x;
    const int wv = tid >> 6, ln = tid & 63;
    const int bm = blockIdx.x * 64, bn = blockIdx.y * 64;
    const int lm = ln & 15, quad = ln >> 4;
    const int wm = (wv & 1) * 32, wn = (wv >> 1) * 32;
    const int r8 = ln >> 3, c8 = ln & 7;

    floatx4 acc[2][2] = {};

    for (int k0 = 0; k0 < K; k0 += 64) {
#pragma unroll
        for (int j = 0; j < 2; ++j) {
            int row = wv * 16 + j * 8 + r8;
            int cg = c8 ^ (row & 7);
            gl_lds16(A + (size_t)(bm + row) * lda + k0 + cg * 8,
                     &As[(wv * 16 + j * 8) * 64]);
        }
#pragma unroll
        for (int j = 0; j < 2; ++j) {
            int row = wv * 16 + j * 8 + r8;
            int cg = c8 ^ (row & 7);
            gl_lds16(W + (size_t)(bn + row) * K + k0 + cg * 8,
                     &Bs[(wv * 16 + j * 8) * 64]);
        }
        __syncthreads();
#pragma unroll
        for (int ks2 = 0; ks2 < 2; ++ks2) {
            int pc = ((quad + ks2 * 4) ^ (lm & 7)) * 8;
            short8 a0 = *(const short8*)&As[(wm + lm) * 64 + pc];
            short8 a1 = *(const short8*)&As[(wm + 16 + lm) * 64 + pc];
            short8 b0 = *(const short8*)&Bs[(wn + lm) * 64 + pc];
            short8 b1 = *(const short8*)&Bs[(wn + 16 + lm) * 64 + pc];
            acc[0][0] = __builtin_amdgcn_mfma_f32_16x16x32_bf16(a0, b0, acc[0][0], 0, 0, 0);
            acc[0][1] = __builtin_amdgcn_mfma_f32_16x16x32_bf16(a0, b1, acc[0][1], 0, 0, 0);
            acc[1][0] = __builtin_amdgcn_mfma_f32_16x16x32_bf16(a1, b0, acc[1][0], 0, 0, 0);
            acc[1][1] = __builtin_amdgcn_mfma_f32_16x16x32_bf16(a1, b1, acc[1][1], 0, 0, 0);
        }
        __syncthreads();
    }

    // C/D layout: col = lane&15, row = quad*4 + reg  [m89-verified]
#pragma unroll
    for (int sm = 0; sm < 2; ++sm) {
#pragma unroll
        for (int sn = 0; sn < 2; ++sn) {
            const int gn = bn + wn + sn * 16 + lm;
            if (gn >= Nz) continue;
#pragma unroll
            for (int r = 0; r < 4; ++r) {
                const int gm = bm + wm + sm * 16 + quad * 4 + r;
                float v;
                if (gn < N) {
                    v = acc[sm][sn][r];
                    if (bias) v += bias[gn];
                    if (ACT == 1) v = fmaxf(v, 0.f);
                    if (ACT == 2) v = softplusf(v);
                    if (addin) v += addin[(size_t)gm * ldc + gn];
                } else {
                    v = 0.f;
                }
                if (OBF)
                    ((ushort_t*)Cv)[(size_t)gm * ldc + gn] = f2bf(v);
                else
                    ((float*)Cv)[(size_t)gm * ldc + gn] = v;
            }
        }
    }
}

// ---------------------------------------------------------------------------
__global__ void init_kernel(const float* __restrict__ qe,
                            const float* __restrict__ pos,
                            float* __restrict__ houtf,
                            float* __restrict__ residual) {
    long idx = (long)blockIdx.x * 256 + threadIdx.x;
    if (idx >= (long)B_ * T_ * E_) return;
    int te = (int)(idx % ((long)T_ * E_));
    houtf[idx] = qe[te] + pos[te];
    residual[idx] = 0.f;
}

// residual += hin; hidden_bf = bf16(rmsnorm(residual) * w)
__global__ __launch_bounds__(256) void add_rmsnorm_kernel(
    const float* __restrict__ hin, float* __restrict__ residual,
    ushort_t* __restrict__ hout, const float* __restrict__ w) {
    const int row = blockIdx.x, tid = threadIdx.x;
    const long base = (long)row * E_;
    __shared__ float red[256];

    float x0 = hin[base + tid] + residual[base + tid];
    bool has1 = (tid + 256 < E_);
    float x1 = has1 ? hin[base + tid + 256] + residual[base + tid + 256] : 0.f;
    residual[base + tid] = x0;
    if (has1) residual[base + tid + 256] = x1;

    red[tid] = x0 * x0 + x1 * x1;
    __syncthreads();
    for (int off = 128; off > 0; off >>= 1) {
        if (tid < off) red[tid] += red[tid + off];
        __syncthreads();
    }
    float sc = rsqrtf(red[0] / E_ + EPS_);
    hout[base + tid] = f2bf(x0 * sc * w[tid]);
    if (has1) hout[base + tid + 256] = f2bf(x1 * sc * w[tid + 256]);
}

// layernorm fp32 in -> bf16 out
__global__ __launch_bounds__(256) void layernorm_kernel(
    const float* __restrict__ x, const float* __restrict__ w,
    const float* __restrict__ b, ushort_t* __restrict__ out) {
    const int row = blockIdx.x, tid = threadIdx.x;
    const long base = (long)row * E_;
    __shared__ float red[256];

    float x0 = x[base + tid];
    bool has1 = (tid + 256 < E_);
    float x1 = has1 ? x[base + tid + 256] : 0.f;

    red[tid] = x0 + x1;
    __syncthreads();
    for (int off = 128; off > 0; off >>= 1) {
        if (tid < off) red[tid] += red[tid + off];
        __syncthreads();
    }
    float mu = red[0] / E_;
    __syncthreads();
    float d0 = x0 - mu, d1 = has1 ? x1 - mu : 0.f;
    red[tid] = d0 * d0 + d1 * d1;
    __syncthreads();
    for (int off = 128; off > 0; off >>= 1) {
        if (tid < off) red[tid] += red[tid + off];
        __syncthreads();
    }
    float sc = rsqrtf(red[0] / E_ + EPS_);
    out[base + tid] = f2bf(d0 * sc * w[tid] + b[tid]);
    if (has1) out[base + tid + 256] = f2bf(d1 * sc * w[tid + 256] + b[tid + 256]);
}

// ---------------------------------------------------------------------------
// depthwise causal conv (DC=4) + bias + SiLU, bf16 in/out, 8 channels/thread
// ---------------------------------------------------------------------------
__global__ __launch_bounds__(256) void conv_silu_kernel(
    const ushort_t* __restrict__ xz, const float* __restrict__ cw,
    const float* __restrict__ cb, ushort_t* __restrict__ xc) {
    int idx = blockIdx.x * 256 + threadIdx.x;  // over B*T*(DI/8)
    if (idx >= B_ * T_ * (DI_ / 8)) return;
    int dc = idx % (DI_ / 8);
    int t = (idx / (DI_ / 8)) % T_;
    int b = idx / ((DI_ / 8) * T_);
    int d0 = dc * 8;

    float4 cwj[8];
#pragma unroll
    for (int j = 0; j < 8; ++j) cwj[j] = *(const float4*)&cw[(d0 + j) * 4];
    float acc[8];
#pragma unroll
    for (int j = 0; j < 8; ++j) acc[j] = cb[d0 + j];

#pragma unroll
    for (int k = 0; k < DC_; ++k) {
        int tt = t + k - (DC_ - 1);
        if (tt < 0) continue;
        uint4 u = *(const uint4*)(xz + (size_t)(b * T_ + tt) * (2 * DI_) + d0);
        float x[8];
        unpack2(u.x, x[0], x[1]); unpack2(u.y, x[2], x[3]);
        unpack2(u.z, x[4], x[5]); unpack2(u.w, x[6], x[7]);
#pragma unroll
        for (int j = 0; j < 8; ++j) {
            float wv = (k == 0) ? cwj[j].x : (k == 1) ? cwj[j].y
                     : (k == 2) ? cwj[j].z : cwj[j].w;
            acc[j] += wv * x[j];
        }
    }
    ushort8v o;
#pragma unroll
    for (int j = 0; j < 8; ++j) o[j] = f2bf(siluf(acc[j]));
    *(ushort8v*)(xc + (size_t)(b * T_ + t) * DI_ + d0) = o;
}

// ---------------------------------------------------------------------------
// selective scan, bf16 I/O; grid (DI/256, B)
// ---------------------------------------------------------------------------
__global__ __launch_bounds__(256) void mamba_scan_kernel(
    const ushort_t* __restrict__ dtb,
    const ushort_t* __restrict__ dbl,
    const ushort_t* __restrict__ xc,
    const ushort_t* __restrict__ xz,
    const float* __restrict__ Alog,
    const float* __restrict__ Dp,
    ushort_t* __restrict__ y) {
    const int d = blockIdx.x * 256 + threadIdx.x;
    const int b = blockIdx.y;
    __shared__ float Bs[T_][DS_];
    __shared__ float Cs[T_][DS_];
    for (int i = threadIdx.x; i < T_ * DS_; i += 256) {
        int t = i >> 4, s = i & 15;
        size_t rb = (size_t)(b * T_ + t) * 64;
        Bs[t][s] = bf2f(dbl[rb + DR_ + s]);
        Cs[t][s] = bf2f(dbl[rb + DR_ + DS_ + s]);
    }
    __syncthreads();

    float Aa[DS_];
#pragma unroll
    for (int s = 0; s < DS_; ++s) Aa[s] = -expf(Alog[(size_t)d * DS_ + s]);
    float h[DS_] = {};
    const float Dv = Dp[d];

    for (int t = 0; t < T_; ++t) {
        size_t idx = (size_t)(b * T_ + t) * DI_ + d;
        float dtv = bf2f(dtb[idx]);
        float xcv = bf2f(xc[idx]);
        float acc = 0.f;
#pragma unroll
        for (int s = 0; s < DS_; ++s) {
            h[s] = expf(dtv * Aa[s]) * h[s] + dtv * Bs[t][s] * xcv;
            acc += h[s] * Cs[t][s];
        }
        float zv = bf2f(xz[(size_t)(b * T_ + t) * (2 * DI_) + DI_ + d]);
        y[idx] = f2bf((acc + Dv * xcv) * siluf(zv));
    }
}

// ---------------------------------------------------------------------------
// cross-attention: one block per (b,h). K/V/Q/scores in LDS (~101 KB).
// ---------------------------------------------------------------------------
__global__ __launch_bounds__(256) void attn_kernel(
    const ushort_t* __restrict__ qh,
    const ushort_t* __restrict__ kh,
    const ushort_t* __restrict__ vh,
    ushort_t* __restrict__ ctx) {
    const int h = blockIdx.x % H_;
    const int b = blockIdx.x / H_;
    const int tid = threadIdx.x;

    __shared__ ushort_t Ks[L_ * HD_];
    __shared__ ushort_t Vs[L_ * HD_];
    __shared__ ushort_t Qs[T_ * HD_];
    __shared__ float Sc[T_ * L_];
    __shared__ float red8[T_][8];
    __shared__ float mx[T_], dn[T_];

    {
        int t = tid >> 3, c = tid & 7;
        *(uint4*)&Qs[t * 64 + c * 8] =
            *(const uint4*)(qh + (size_t)(b * T_ + t) * E_ + h * HD_ + c * 8);
    }
    {
        int s = tid;
        const ushort_t* kr = kh + (size_t)(b * L_ + s) * E_ + h * HD_;
        const ushort_t* vr = vh + (size_t)(b * L_ + s) * E_ + h * HD_;
#pragma unroll
        for (int c = 0; c < 8; ++c) {
            int cp = (c ^ (s & 7)) * 8;
            *(uint4*)&Ks[s * 64 + cp] = *(const uint4*)(kr + c * 8);
            *(uint4*)&Vs[s * 64 + cp] = *(const uint4*)(vr + c * 8);
        }
    }
    __syncthreads();

    {
        int s = tid;
        float kr[64];
#pragma unroll
        for (int c = 0; c < 8; ++c) {
            int cp = (c ^ (s & 7)) * 8;
            uint4 u = *(const uint4*)&Ks[s * 64 + cp];
            unpack2(u.x, kr[c * 8 + 0], kr[c * 8 + 1]);
            unpack2(u.y, kr[c * 8 + 2], kr[c * 8 + 3]);
            unpack2(u.z, kr[c * 8 + 4], kr[c * 8 + 5]);
            unpack2(u.w, kr[c * 8 + 6], kr[c * 8 + 7]);
        }
        for (int t = 0; t < T_; ++t) {
            float d = 0.f;
#pragma unroll
            for (int c = 0; c < 8; ++c) {
                uint4 qu = *(const uint4*)&Qs[t * 64 + c * 8];
                float q0, q1, q2, q3, q4, q5, q6, q7;
                unpack2(qu.x, q0, q1); unpack2(qu.y, q2, q3);
                unpack2(qu.z, q4, q5); unpack2(qu.w, q6, q7);
                d += q0 * kr[c * 8 + 0] + q1 * kr[c * 8 + 1] +
                     q2 * kr[c * 8 + 2] + q3 * kr[c * 8 + 3] +
                     q4 * kr[c * 8 + 4] + q5 * kr[c * 8 + 5] +
                     q6 * kr[c * 8 + 6] + q7 * kr[c * 8 + 7];
            }
            Sc[t * L_ + s] = d * 0.125f;
        }
    }
    __syncthreads();

    {
        int t = tid >> 3, j = tid & 7;
        float m = -1e30f;
        for (int s = j * 32; s < j * 32 + 32; ++s) m = fmaxf(m, Sc[t * L_ + s]);
        red8[t][j] = m;
    }
    __syncthreads();
    if (tid < T_) {
        float m = red8[tid][0];
#pragma unroll
        for (int j = 1; j < 8; ++j) m = fmaxf(m, red8[tid][j]);
        mx[tid] = m;
    }
    __syncthreads();
    {
        int t = tid >> 3, j = tid & 7;
        float m = mx[t], sum = 0.f;
        for (int s = j * 32; s < j * 32 + 32; ++s) {
            float e = expf(Sc[t * L_ + s] - m);
            Sc[t * L_ + s] = e;
            sum += e;
        }
        red8[t][j] = sum;
    }
    __syncthreads();
    if (tid < T_) {
        float s = 0.f;
#pragma unroll
        for (int j = 0; j < 8; ++j) s += red8[tid][j];
        dn[tid] = 1.f / s;
    }
    __syncthreads();

    {
        int t = tid >> 3, c = tid & 7;
        float o[8] = {};
        for (int si = 0; si < L_; ++si) {
            int s = (si + t * 33) & (L_ - 1);
            float p = Sc[t * L_ + s];
            int cp = (c ^ (s & 7)) * 8;
            uint4 u = *(const uint4*)&Vs[s * 64 + cp];
            float v0, v1, v2, v3, v4, v5, v6, v7;
            unpack2(u.x, v0, v1); unpack2(u.y, v2, v3);
            unpack2(u.z, v4, v5); unpack2(u.w, v6, v7);
            o[0] += p * v0; o[1] += p * v1; o[2] += p * v2; o[3] += p * v3;
            o[4] += p * v4; o[5] += p * v5; o[6] += p * v6; o[7] += p * v7;
        }
        float sc = dn[t];
        ushort8v pk;
#pragma unroll
        for (int j = 0; j < 8; ++j) pk[j] = f2bf(o[j] * sc);
        *(ushort8v*)(ctx + (size_t)(b * T_ + t) * E_ + h * HD_ + c * 8) = pk;
    }
}

// ---------------------------------------------------------------------------
static void gemm(hipStream_t s, int act, int obf, const ushort_t* A, int lda,
                 const ushort_t* W, const float* bias, const float* addin,
                 void* C, int M, int N, int K, int Nz, int ldc) {
    dim3 g(M / 64, (Nz + 63) / 64), b(256);
    if (obf) {
        switch (act) {
            case 0: gemm_bf16<0, 1><<<g, b, 0, s>>>(A, lda, W, bias, addin, C, M, N, K, Nz, ldc); break;
            case 1: gemm_bf16<1, 1><<<g, b, 0, s>>>(A, lda, W, bias, addin, C, M, N, K, Nz, ldc); break;
            case 2: gemm_bf16<2, 1><<<g, b, 0, s>>>(A, lda, W, bias, addin, C, M, N, K, Nz, ldc); break;
        }
    } else {
        gemm_bf16<0, 0><<<g, b, 0, s>>>(A, lda, W, bias, addin, C, M, N, K, Nz, ldc);
    }
}

static void cvt(hipStream_t s, const float* src, ushort_t* dst, long n) {
    long n4 = n / 4;
    cvt_bf16_kernel<<<(int)((n4 + 255) / 256), 256, 0, s>>>(src, dst, n4);
}
static void cvt_pad(hipStream_t s, const float* src, ushort_t* dst,
                    int sr, int sc, int dr, int dc, int layers) {
    long total = (long)layers * dr * dc;
    cvt_pad_kernel<<<(int)((total + 255) / 256), 256, 0, s>>>(src, dst, sr, sc, dr, dc, layers);
}

extern "C" void kernel_launch(void* const* d_in, const int* in_sizes, int n_in,
                              void* d_out, int out_size, void* d_ws, size_t ws_size,
                              hipStream_t stream) {
    const float* enc      = (const float*)d_in[0];
    const float* qe       = (const float*)d_in[1];
    const float* pos      = (const float*)d_in[2];
    const float* m_norm_w = (const float*)d_in[3];
    const float* m_in_w   = (const float*)d_in[4];
    const float* m_conv_w = (const float*)d_in[5];
    const float* m_conv_b = (const float*)d_in[6];
    const float* m_xproj_w= (const float*)d_in[7];
    const float* m_dt_w   = (const float*)d_in[8];
    const float* m_dt_b   = (const float*)d_in[9];
    const float* m_Alog   = (const float*)d_in[10];
    const float* m_D      = (const float*)d_in[11];
    const float* m_out_w  = (const float*)d_in[12];
    const float* rms_w    = (const float*)d_in[13];
    const float* wq = (const float*)d_in[14];
    const float* bq = (const float*)d_in[15];
    const float* wk = (const float*)d_in[16];
    const float* bk = (const float*)d_in[17];
    const float* wv = (const float*)d_in[18];
    const float* bv = (const float*)d_in[19];
    const float* wo = (const float*)d_in[20];
    const float* bo = (const float*)d_in[21];
    const float* ln1_w = (const float*)d_in[22];
    const float* ln1_b = (const float*)d_in[23];
    const float* ffn_w1 = (const float*)d_in[24];
    const float* ffn_b1 = (const float*)d_in[25];
    const float* ffn_w2 = (const float*)d_in[26];
    const float* ffn_b2 = (const float*)d_in[27];
    const float* ln2_w = (const float*)d_in[28];
    const float* ln2_b = (const float*)d_in[29];
    const float* out_w = (const float*)d_in[30];
    const float* out_b = (const float*)d_in[31];

    const long SZ_BTE = (long)B_ * T_ * E_;  // 786432
    float* residual = (float*)d_ws;
    float* houtf    = residual + SZ_BTE;

    ushort_t* u = (ushort_t*)(houtf + SZ_BTE);
    ushort_t* hidden = u;                    // 786,432
    ushort_t* S      = hidden + SZ_BTE;      // union region, 7,995,392 us
    // mamba-phase layout:
    ushort_t* xz  = S;                       // 3,145,728
    ushort_t* xc  = xz + 3145728;            // 1,572,864
    ushort_t* dbl = xc + 1572864;            //   131,072 (2048 x 64 padded)
    ushort_t* dtb = dbl + 131072;            // 1,572,864
    ushort_t* yb  = dtb + 1572864;           // 1,572,864
    // attention-phase aliases:
    ushort_t* enc_bf = S;                    // 6,291,456
    ushort_t* qh  = S + 6291456;             //   786,432
    ushort_t* ctx = qh + 786432;             //   786,432
    // ffn alias:
    ushort_t* ffnb = S;                      // 3,145,728
    ushort_t* kh = S + 7995392;              // 6,291,456
    ushort_t* vh = kh + 6291456;             // 6,291,456

    // bf16 weights (padded where needed)
    ushort_t* w_in    = vh + 6291456;        // 7,077,888
    ushort_t* w_xproj = w_in + 7077888;      // 12*64*768 (rows 56..63 zero)
    ushort_t* w_dt    = w_xproj + 589824;    // 12*768*64 (cols 24..63 zero)
    ushort_t* w_out   = w_dt + 589824;       // 3,538,944
    ushort_t* w_q     = w_out + 3538944;
    ushort_t* w_k     = w_q + 147456;
    ushort_t* w_v     = w_k + 147456;
    ushort_t* w_o     = w_v + 147456;
    ushort_t* w_f1    = w_o + 147456;
    ushort_t* w_f2    = w_f1 + 589824;
    ushort_t* w_lg    = w_f2 + 589824;       // 128*384 (rows 97..127 zero)

    const int M  = B_ * T_;   // 2048
    const int MK = B_ * L_;   // 16384

    // ---- weight conversion (every launch) ----
    cvt(stream, m_in_w,  w_in,  7077888);
    cvt_pad(stream, m_xproj_w, w_xproj, 56, 768, 64, 768, 12);
    cvt_pad(stream, m_dt_w,    w_dt,    768, 24, 768, 64, 12);
    cvt(stream, m_out_w, w_out, 3538944);
    cvt(stream, wq, w_q, 147456);
    cvt(stream, wk, w_k, 147456);
    cvt(stream, wv, w_v, 147456);
    cvt(stream, wo, w_o, 147456);
    cvt(stream, ffn_w1, w_f1, 589824);
    cvt(stream, ffn_w2, w_f2, 589824);
    cvt_pad(stream, out_w, w_lg, 97, 384, 128, 384, 1);

    init_kernel<<<(int)((SZ_BTE + 255) / 256), 256, 0, stream>>>(qe, pos, houtf, residual);

    for (int l = 0; l < ND_; ++l) {
        add_rmsnorm_kernel<<<M, 256, 0, stream>>>(houtf, residual, hidden,
                                                  m_norm_w + (long)l * E_);
        gemm(stream, 0, 1, hidden, E_, w_in + (long)l * 1536 * 384,
             nullptr, nullptr, xz, M, 1536, 384, 1536, 1536);
        conv_silu_kernel<<<(M * (DI_ / 8) + 255) / 256, 256, 0, stream>>>(
            xz, m_conv_w + (long)l * DI_ * DC_, m_conv_b + (long)l * DI_, xc);
        gemm(stream, 0, 1, xc, DI_, w_xproj + (long)l * 64 * 768,
             nullptr, nullptr, dbl, M, 56, 768, 64, 64);
        gemm(stream, 2, 1, dbl, 64, w_dt + (long)l * 768 * 64,
             m_dt_b + (long)l * DI_, nullptr, dtb, M, 768, 64, 768, 768);
        mamba_scan_kernel<<<dim3(DI_ / 256, B_), 256, 0, stream>>>(
            dtb, dbl, xc, xz, m_Alog + (long)l * DI_ * DS_, m_D + (long)l * DI_, yb);
        gemm(stream, 0, 0, yb, DI_, w_out + (long)l * 384 * 768,
             nullptr, nullptr, houtf, M, 384, 768, 384, 384);
    }

    add_rmsnorm_kernel<<<M, 256, 0, stream>>>(houtf, residual, hidden, rms_w);

    gemm(stream, 0, 1, hidden, E_, w_q, bq, nullptr, qh, M, 384, 384, 384, 384);
    cvt(stream, enc, enc_bf, (long)MK * E_);
    gemm(stream, 0, 1, enc_bf, E_, w_k, bk, nullptr, kh, MK, 384, 384, 384, 384);
    gemm(stream, 0, 1, enc_bf, E_, w_v, bv, nullptr, vh, MK, 384, 384, 384, 384);
    attn_kernel<<<B_ * H_, 256, 0, stream>>>(qh, kh, vh, ctx);
    gemm(stream, 0, 0, ctx, E_, w_o, bo, residual, residual, M, 384, 384, 384, 384);

    layernorm_kernel<<<M, 256, 0, stream>>>(residual, ln1_w, ln1_b, hidden);
    gemm(stream, 1, 1, hidden, E_, w_f1, ffn_b1, nullptr, ffnb, M, 1536, 384, 1536, 1536);
    gemm(stream, 0, 0, ffnb, HID_, w_f2, ffn_b2, residual, residual, M, 384, 1536, 384, 384);
    layernorm_kernel<<<M, 256, 0, stream>>>(residual, ln2_w, ln2_b, hidden);

    gemm(stream, 0, 0, hidden, E_, w_lg, out_b, nullptr, (float*)d_out, M, V_, 384, V_, V_);
}